// Round 10
// baseline (251.800 us; speedup 1.0000x reference)
//
#include <hip/hip_runtime.h>
#include <hip/hip_bf16.h>
#include <math.h>

#define B_ 256
#define T_ 256
#define I_ 2048
#define H_ 128

#define BM 128
#define BK 32
#define NKT (I_ / BK)   // 64 K-tiles

typedef __attribute__((ext_vector_type(8))) short bf16x8;
typedef __attribute__((ext_vector_type(4))) float f32x4;
typedef _Float16 half2v __attribute__((ext_vector_type(2)));

static __device__ inline short f2bf(float f) {
    __hip_bfloat16 h = __float2bfloat16(f);
    return *reinterpret_cast<short*>(&h);
}

static __device__ inline bf16x8 pack8(float4 a, float4 b) {
    bf16x8 r;
    r[0] = f2bf(a.x); r[1] = f2bf(a.y); r[2] = f2bf(a.z); r[3] = f2bf(a.w);
    r[4] = f2bf(b.x); r[5] = f2bf(b.y); r[6] = f2bf(b.z); r[7] = f2bf(b.w);
    return r;
}

// ---------------------------------------------------------------------------
// Kernel 1 (UNCHANGED from R5): bf16 MFMA projection, global_load_lds
// staging, dbuf LDS, XOR-swizzle both-sides, 1 barrier/K-step.
// ---------------------------------------------------------------------------
__global__ __launch_bounds__(256, 2) void proj_mfma(
    const float* __restrict__ x, const float* __restrict__ Wih,
    const float* __restrict__ bih, const float* __restrict__ bhh,
    float* __restrict__ xp)
{
    __shared__ __align__(16) float As[2][BM * BK];
    __shared__ __align__(16) float Bs[2][H_ * BK];

    const int tid  = threadIdx.x;
    const int lane = tid & 63;
    const int wid  = tid >> 6;
    const int wr   = wid >> 1;
    const int wc   = wid & 1;
    const long row0 = (long)blockIdx.x * BM;

    const int srow  = lane >> 3;
    const int sunit = (lane & 7) ^ srow;

    f32x4 acc[4][4];
    #pragma unroll
    for (int m = 0; m < 4; ++m)
        #pragma unroll
        for (int n = 0; n < 4; ++n)
            acc[m][n] = (f32x4){0.f, 0.f, 0.f, 0.f};

    const int fr = lane & 15;
    const int fq = lane >> 4;
    const int rb0 = wid * 32;

    #pragma unroll
    for (int i = 0; i < 4; ++i) {
        const int rbase = rb0 + i * 8;
        const float* ga = x   + (row0 + rbase + srow) * I_ + sunit * 4;
        const float* gb = Wih + (long)(rbase + srow) * I_ + sunit * 4;
        __builtin_amdgcn_global_load_lds(
            (const __attribute__((address_space(1))) void*)ga,
            (__attribute__((address_space(3))) void*)&As[0][rbase * BK], 16, 0, 0);
        __builtin_amdgcn_global_load_lds(
            (const __attribute__((address_space(1))) void*)gb,
            (__attribute__((address_space(3))) void*)&Bs[0][rbase * BK], 16, 0, 0);
    }
    __syncthreads();

    int p = 0;
    for (int t = 0; t < NKT; ++t) {
        if (t + 1 < NKT) {
            const int kk = (t + 1) * BK;
            #pragma unroll
            for (int i = 0; i < 4; ++i) {
                const int rbase = rb0 + i * 8;
                const float* ga = x   + (row0 + rbase + srow) * I_ + kk + sunit * 4;
                const float* gb = Wih + (long)(rbase + srow) * I_ + kk + sunit * 4;
                __builtin_amdgcn_global_load_lds(
                    (const __attribute__((address_space(1))) void*)ga,
                    (__attribute__((address_space(3))) void*)&As[p ^ 1][rbase * BK], 16, 0, 0);
                __builtin_amdgcn_global_load_lds(
                    (const __attribute__((address_space(1))) void*)gb,
                    (__attribute__((address_space(3))) void*)&Bs[p ^ 1][rbase * BK], 16, 0, 0);
            }
        }
        bf16x8 af[4], bfr[4];
        #pragma unroll
        for (int f = 0; f < 4; ++f) {
            const int ra_ = wr * 64 + f * 16 + fr;
            const float4 a0 = *reinterpret_cast<const float4*>(
                &As[p][ra_ * BK + (((fq * 2)     ^ (ra_ & 7)) * 4)]);
            const float4 a1 = *reinterpret_cast<const float4*>(
                &As[p][ra_ * BK + (((fq * 2 + 1) ^ (ra_ & 7)) * 4)]);
            af[f] = pack8(a0, a1);
            const int rb_ = wc * 64 + f * 16 + fr;
            const float4 b0 = *reinterpret_cast<const float4*>(
                &Bs[p][rb_ * BK + (((fq * 2)     ^ (rb_ & 7)) * 4)]);
            const float4 b1 = *reinterpret_cast<const float4*>(
                &Bs[p][rb_ * BK + (((fq * 2 + 1) ^ (rb_ & 7)) * 4)]);
            bfr[f] = pack8(b0, b1);
        }
        #pragma unroll
        for (int m = 0; m < 4; ++m)
            #pragma unroll
            for (int n = 0; n < 4; ++n)
                acc[m][n] = __builtin_amdgcn_mfma_f32_16x16x32_bf16(
                    af[m], bfr[n], acc[m][n], 0, 0, 0);
        __syncthreads();
        p ^= 1;
    }

    #pragma unroll
    for (int n = 0; n < 4; ++n) {
        const int col = wc * 64 + n * 16 + fr;
        const float bn = bih[col] + bhh[col];
        #pragma unroll
        for (int m = 0; m < 4; ++m) {
            const long rbase = row0 + wr * 64 + m * 16 + fq * 4;
            #pragma unroll
            for (int j = 0; j < 4; ++j)
                xp[(rbase + j) * H_ + col] = acc[m][n][j] + bn;
        }
    }
}

// ---------------------------------------------------------------------------
// Kernel 2 (single-wave scan): 256 blocks x 64 threads (ONE wave per block,
// one CU each). Thread l owns rows j=2l, 2l+1; both W_hh rows live in VGPRs
// as 128 packed-f16 pairs. Each step: read ALL of h (256 B, 16 ds_read_b128
// broadcast), 128 v_dot2_f32_f16, 2 tanh, pack both h's into one b32 write.
// NO barriers, NO shfl in the loop — single wave is lockstep, LDS program
// order is preserved. xp read as float2 (adjacent j), 4-deep prefetch.
// ---------------------------------------------------------------------------
__global__ __launch_bounds__(64, 1) void scan_kernel(
    const float* __restrict__ xp, const float* __restrict__ Whh,
    const float* __restrict__ Wfc, const float* __restrict__ bfc,
    float* __restrict__ out)
{
    __shared__ __align__(16) unsigned hpk[2][H_ / 2];   // 64 u32 = 128 f16, dbuf

    const int l = threadIdx.x;     // 0..63
    const int b = blockIdx.x;
    const int j0 = 2 * l;

    // W_hh rows j0, j0+1 -> packed f16 pairs (pair q = k 2q,2q+1)
    half2v W0[64], W1[64];
    {
        const float4* w0 = reinterpret_cast<const float4*>(&Whh[(long)j0 * H_]);
        const float4* w1 = reinterpret_cast<const float4*>(&Whh[(long)(j0 + 1) * H_]);
        #pragma unroll
        for (int q = 0; q < 32; ++q) {
            const float4 a = w0[q];
            const float4 c = w1[q];
            half2v p0, p1, p2, p3;
            p0[0] = (_Float16)a.x; p0[1] = (_Float16)a.y;
            p1[0] = (_Float16)a.z; p1[1] = (_Float16)a.w;
            p2[0] = (_Float16)c.x; p2[1] = (_Float16)c.y;
            p3[0] = (_Float16)c.z; p3[1] = (_Float16)c.w;
            W0[2 * q] = p0; W0[2 * q + 1] = p1;
            W1[2 * q] = p2; W1[2 * q + 1] = p3;
        }
    }
    hpk[0][l] = 0u;
    __builtin_amdgcn_wave_barrier();

    const float2* xprow2 = reinterpret_cast<const float2*>(xp + (long)b * T_ * H_) + l;
    float2 xa = xprow2[0 * 64];
    float2 xb = xprow2[1 * 64];
    float2 xc = xprow2[2 * 64];
    float2 xd = xprow2[3 * 64];

    auto body = [&](int t, float2 xpv) {
        const uint4* hp = reinterpret_cast<const uint4*>(&hpk[t & 1][0]);
        float a0 = 0.f, a1 = 0.f, c0 = 0.f, c1 = 0.f;
        #pragma unroll
        for (int q = 0; q < 16; ++q) {
            const uint4 u = hp[q];   // 8 f16: k = 8q .. 8q+7
            const half2v h0 = __builtin_bit_cast(half2v, u.x);
            const half2v h1 = __builtin_bit_cast(half2v, u.y);
            const half2v h2 = __builtin_bit_cast(half2v, u.z);
            const half2v h3 = __builtin_bit_cast(half2v, u.w);
            a0 = __builtin_amdgcn_fdot2(h0, W0[4*q+0], a0, false);
            a1 = __builtin_amdgcn_fdot2(h1, W0[4*q+1], a1, false);
            a0 = __builtin_amdgcn_fdot2(h2, W0[4*q+2], a0, false);
            a1 = __builtin_amdgcn_fdot2(h3, W0[4*q+3], a1, false);
            c0 = __builtin_amdgcn_fdot2(h0, W1[4*q+0], c0, false);
            c1 = __builtin_amdgcn_fdot2(h1, W1[4*q+1], c1, false);
            c0 = __builtin_amdgcn_fdot2(h2, W1[4*q+2], c0, false);
            c1 = __builtin_amdgcn_fdot2(h3, W1[4*q+3], c1, false);
        }
        const float pre0 = (a0 + a1) + xpv.x;
        const float pre1 = (c0 + c1) + xpv.y;
        const float e0 = __expf(2.f * pre0);    // tanh = 1 - 2/(e^{2x}+1)
        const float e1 = __expf(2.f * pre1);
        half2v hh;
        hh[0] = (_Float16)(1.f - 2.f / (e0 + 1.f));
        hh[1] = (_Float16)(1.f - 2.f / (e1 + 1.f));
        hpk[(t + 1) & 1][l] = __builtin_bit_cast(unsigned, hh);
        __builtin_amdgcn_wave_barrier();        // ordering only; zero cost
    };

    for (int t = 0; t < T_; t += 4) {
        float2 xu;
        xu = xa; if (t + 4 < T_) xa = xprow2[(long)(t + 4) * 64];
        body(t + 0, xu);
        xu = xb; if (t + 5 < T_) xb = xprow2[(long)(t + 5) * 64];
        body(t + 1, xu);
        xu = xc; if (t + 6 < T_) xc = xprow2[(long)(t + 6) * 64];
        body(t + 2, xu);
        xu = xd; if (t + 7 < T_) xd = xprow2[(long)(t + 7) * 64];
        body(t + 3, xu);
    }

    // final FC: h_T is in hpk[0] (t=255 wrote (255+1)&1 = 0)
    {
        const unsigned u = hpk[0][l];           // pair h[2l], h[2l+1]
        const half2v hh = __builtin_bit_cast(half2v, u);
        const float2 wf = reinterpret_cast<const float2*>(Wfc)[l];
        float v = (float)hh[0] * wf.x + (float)hh[1] * wf.y;
        #pragma unroll
        for (int off = 32; off > 0; off >>= 1) v += __shfl_down(v, off);
        if (l == 0) out[b] = v + bfc[0];
    }
}

// ---------------------------------------------------------------------------
extern "C" void kernel_launch(void* const* d_in, const int* in_sizes, int n_in,
                              void* d_out, int out_size, void* d_ws, size_t ws_size,
                              hipStream_t stream)
{
    const float* x   = (const float*)d_in[0];
    const float* Wih = (const float*)d_in[1];
    const float* Whh = (const float*)d_in[2];
    const float* bih = (const float*)d_in[3];
    const float* bhh = (const float*)d_in[4];
    const float* Wfc = (const float*)d_in[5];
    const float* bfc = (const float*)d_in[6];
    float* out = (float*)d_out;
    float* xp  = (float*)d_ws;   // 65536 * 128 floats = 32 MB scratch

    proj_mfma<<<dim3((B_ * T_) / BM), dim3(256), 0, stream>>>(x, Wih, bih, bhh, xp);
    scan_kernel<<<dim3(B_), dim3(64), 0, stream>>>(xp, Whh, Wfc, bfc, out);
}

// Round 11
// 240.965 us; speedup vs baseline: 1.0450x; 1.0450x over previous
//
#include <hip/hip_runtime.h>
#include <hip/hip_bf16.h>
#include <math.h>

#define B_ 256
#define T_ 256
#define I_ 2048
#define H_ 128

#define BM 128
#define BK 32
#define NKT (I_ / BK)   // 64 K-tiles
#define NBUF 3

typedef __attribute__((ext_vector_type(8))) short bf16x8;
typedef __attribute__((ext_vector_type(4))) float f32x4;
typedef _Float16 half2v __attribute__((ext_vector_type(2)));

static __device__ inline short f2bf(float f) {
    __hip_bfloat16 h = __float2bfloat16(f);
    return *reinterpret_cast<short*>(&h);
}

static __device__ inline bf16x8 pack8(float4 a, float4 b) {
    bf16x8 r;
    r[0] = f2bf(a.x); r[1] = f2bf(a.y); r[2] = f2bf(a.z); r[3] = f2bf(a.w);
    r[4] = f2bf(b.x); r[5] = f2bf(b.y); r[6] = f2bf(b.z); r[7] = f2bf(b.w);
    return r;
}

// barrier that drains ONLY lgkm (DS) — leaves global prefetch in flight
#define LGKM_BARRIER() do {                                  \
    asm volatile("s_waitcnt lgkmcnt(0)" ::: "memory");       \
    __builtin_amdgcn_sched_barrier(0);                       \
    __builtin_amdgcn_s_barrier();                            \
} while (0)

// B-tile row swizzle (4 units of 16B per 64B row)
static __device__ inline int sB(int r) { return (r & 3) ^ ((r >> 2) & 3); }

// ---------------------------------------------------------------------------
// Pre-kernel (proven R4): W_ih fp32 [128][2048] -> bf16, L2-resident.
// ---------------------------------------------------------------------------
__global__ __launch_bounds__(256) void convW(
    const float* __restrict__ W, short* __restrict__ Wb)
{
    const int g = blockIdx.x * 256 + threadIdx.x;
    const float4 v0 = reinterpret_cast<const float4*>(W)[2 * g];
    const float4 v1 = reinterpret_cast<const float4*>(W)[2 * g + 1];
    reinterpret_cast<bf16x8*>(Wb)[g] = pack8(v0, v1);
}

// ---------------------------------------------------------------------------
// Kernel 1 v2: bf16 MFMA projection with T3/T4-style pipeline.
//   - A (x, fp32) staged via global_load_lds, 3 buffers, XOR-swz (unit^row&7)
//   - B (W_ih, bf16 via convW) staged via global_load_lds, 3 buffers,
//     swz unit ^ sB(row); frags read DIRECTLY as bf16x8 (no cvt)
//   - counted s_waitcnt vmcnt(6): 2 stages stay in flight across raw
//     s_barriers (no vmcnt(0) drain in the loop)
//   - bias loaded BEFORE staging so in-loop vmcnt counting is exact
// ---------------------------------------------------------------------------
__global__ __launch_bounds__(256, 2) void proj_mfma(
    const float* __restrict__ x, const short* __restrict__ Wb,
    const float* __restrict__ bih, const float* __restrict__ bhh,
    float* __restrict__ xp)
{
    __shared__ __align__(16) float As[NBUF][BM * BK];   // 3 x 16 KB
    __shared__ __align__(16) short Bs[NBUF][H_ * BK];   // 3 x 8 KB

    const int tid  = threadIdx.x;
    const int lane = tid & 63;
    const int wid  = tid >> 6;
    const int wr   = wid >> 1;
    const int wc   = wid & 1;
    const long row0 = (long)blockIdx.x * BM;

    const int fr = lane & 15;
    const int fq = lane >> 4;

    // bias FIRST (vmem retires before staging; keeps vmcnt counting exact)
    float biasr[4];
    #pragma unroll
    for (int n = 0; n < 4; ++n) {
        const int col = wc * 64 + n * 16 + fr;
        biasr[n] = bih[col] + bhh[col];
    }

    // A staging decode: 4 loads, 8-row chunks
    const int srow  = lane >> 3;              // 0..7
    const int sunitA = (lane & 7) ^ srow;     // swizzled source unit
    const int rb0 = wid * 32;
    // B staging decode: 2 loads
    const int bu = lane & 3;

    auto STAGE = [&](int tt, int buf) {
        const int kk = tt * BK;
        #pragma unroll
        for (int i = 0; i < 4; ++i) {
            const int rbase = rb0 + i * 8;
            const float* ga = x + (row0 + rbase + srow) * I_ + kk + sunitA * 4;
            __builtin_amdgcn_global_load_lds(
                (const __attribute__((address_space(1))) void*)ga,
                (__attribute__((address_space(3))) void*)&As[buf][rbase * BK], 16, 0, 0);
        }
        #pragma unroll
        for (int i = 0; i < 2; ++i) {
            const int brow = wid * 32 + i * 16 + (lane >> 2);
            const int bswz = bu ^ sB(brow);
            const short* gb = Wb + (long)brow * I_ + kk + bswz * 8;
            __builtin_amdgcn_global_load_lds(
                (const __attribute__((address_space(1))) void*)gb,
                (__attribute__((address_space(3))) void*)&Bs[buf][(wid * 128 + i * 64) * 8], 16, 0, 0);
        }
    };

    f32x4 acc[4][4];
    #pragma unroll
    for (int m = 0; m < 4; ++m)
        #pragma unroll
        for (int n = 0; n < 4; ++n)
            acc[m][n] = (f32x4){0.f, 0.f, 0.f, 0.f};

    // prologue: two stages in flight
    STAGE(0, 0);
    STAGE(1, 1);

    for (int t = 0; t < NKT; ++t) {
        const int p = t % 3;
        // wait for THIS tile's 6 loads (2 newer stages = 12 may stay in flight)
        if (t == NKT - 1) { asm volatile("s_waitcnt vmcnt(0)" ::: "memory"); }
        else              { asm volatile("s_waitcnt vmcnt(6)" ::: "memory"); }
        __builtin_amdgcn_sched_barrier(0);
        __builtin_amdgcn_s_barrier();           // all waves: tile t resident
        __builtin_amdgcn_sched_barrier(0);

        bf16x8 af[4], bfr[4];
        #pragma unroll
        for (int f = 0; f < 4; ++f) {
            const int ra_ = wr * 64 + f * 16 + fr;
            const float4 a0 = *reinterpret_cast<const float4*>(
                &As[p][ra_ * BK + (((fq * 2)     ^ (ra_ & 7)) * 4)]);
            const float4 a1 = *reinterpret_cast<const float4*>(
                &As[p][ra_ * BK + (((fq * 2 + 1) ^ (ra_ & 7)) * 4)]);
            af[f] = pack8(a0, a1);
            const int rb_ = wc * 64 + f * 16 + fr;
            bfr[f] = *reinterpret_cast<const bf16x8*>(
                &Bs[p][rb_ * 32 + ((fq ^ sB(rb_)) * 8)]);
        }
        #pragma unroll
        for (int m = 0; m < 4; ++m)
            #pragma unroll
            for (int n = 0; n < 4; ++n)
                acc[m][n] = __builtin_amdgcn_mfma_f32_16x16x32_bf16(
                    af[m], bfr[n], acc[m][n], 0, 0, 0);

        __builtin_amdgcn_s_barrier();           // all waves done READING tile t
        __builtin_amdgcn_sched_barrier(0);
        if (t + 2 < NKT) STAGE(t + 2, (t + 2) % 3);   // overwrites buf (t-1)%3
    }

    // epilogue: bias + store (C layout: row=(lane>>4)*4+j, col=lane&15)
    #pragma unroll
    for (int n = 0; n < 4; ++n) {
        const int col = wc * 64 + n * 16 + fr;
        #pragma unroll
        for (int m = 0; m < 4; ++m) {
            const long rbase = row0 + wr * 64 + m * 16 + fq * 4;
            #pragma unroll
            for (int j = 0; j < 4; ++j)
                xp[(rbase + j) * H_ + col] = acc[m][n][j] + biasr[n];
        }
    }
}

// ---------------------------------------------------------------------------
// Kernel 2 v2 (2-wave scan): 256 blocks x 128 threads. Thread = one j row;
// W_hh[j] as 64 packed-f16 pairs in VGPRs; each step reads ALL of h (16
// broadcast ds_read_b128), 64 fdot2 over 4 acc chains — NO shfl, NO k-split.
// lgkm-only barrier between the 2 waves; 4-deep xp prefetch.
// ---------------------------------------------------------------------------
__global__ __launch_bounds__(128, 1) void scan_kernel(
    const float* __restrict__ xp, const float* __restrict__ Whh,
    const float* __restrict__ Wfc, const float* __restrict__ bfc,
    float* __restrict__ out)
{
    __shared__ __align__(16) unsigned hpk[2][H_ / 2];   // 64 u32 = 128 f16, dbuf

    const int j = threadIdx.x;     // 0..127
    const int b = blockIdx.x;

    // W_hh row j -> 64 packed f16 pairs (pair q = k 2q,2q+1)
    half2v W[64];
    {
        const float4* wp = reinterpret_cast<const float4*>(&Whh[(long)j * H_]);
        #pragma unroll
        for (int q = 0; q < 32; ++q) {
            const float4 wv = wp[q];
            half2v p0, p1;
            p0[0] = (_Float16)wv.x; p0[1] = (_Float16)wv.y;
            p1[0] = (_Float16)wv.z; p1[1] = (_Float16)wv.w;
            W[2 * q]     = p0;
            W[2 * q + 1] = p1;
        }
    }
    if (j < H_ / 2) hpk[0][j] = 0u;

    const float* xprow = xp + (long)b * T_ * H_ + j;
    float xa = xprow[0 * H_];
    float xb = xprow[1 * H_];
    float xc = xprow[2 * H_];
    float xd = xprow[3 * H_];
    __syncthreads();

    auto body = [&](int t, float xpv) {
        const uint4* hp = reinterpret_cast<const uint4*>(&hpk[t & 1][0]);
        float a0 = 0.f, a1 = 0.f, a2 = 0.f, a3 = 0.f;
        #pragma unroll
        for (int q = 0; q < 16; ++q) {
            const uint4 u = hp[q];   // 8 f16: k = 8q..8q+7 (broadcast read)
            a0 = __builtin_amdgcn_fdot2(__builtin_bit_cast(half2v, u.x), W[4*q+0], a0, false);
            a1 = __builtin_amdgcn_fdot2(__builtin_bit_cast(half2v, u.y), W[4*q+1], a1, false);
            a2 = __builtin_amdgcn_fdot2(__builtin_bit_cast(half2v, u.z), W[4*q+2], a2, false);
            a3 = __builtin_amdgcn_fdot2(__builtin_bit_cast(half2v, u.w), W[4*q+3], a3, false);
        }
        const float pre = ((a0 + a1) + (a2 + a3)) + xpv;
        const float e = __expf(2.f * pre);      // tanh = 1 - 2/(e^{2x}+1)
        const float h = 1.f - 2.f / (e + 1.f);
        reinterpret_cast<unsigned short*>(&hpk[(t + 1) & 1][0])[j] =
            __builtin_bit_cast(unsigned short, (_Float16)h);
        LGKM_BARRIER();                         // DS-drain only; vmem in flight
    };

    for (int t = 0; t < T_; t += 4) {
        float xu;
        xu = xa; if (t + 4 < T_) xa = xprow[(long)(t + 4) * H_];
        body(t + 0, xu);
        xu = xb; if (t + 5 < T_) xb = xprow[(long)(t + 5) * H_];
        body(t + 1, xu);
        xu = xc; if (t + 6 < T_) xc = xprow[(long)(t + 6) * H_];
        body(t + 2, xu);
        xu = xd; if (t + 7 < T_) xd = xprow[(long)(t + 7) * H_];
        body(t + 3, xu);
    }

    // final FC: h_T is in hpk[0] (t=255 wrote (255+1)&1 = 0)
    if (j < 64) {
        const unsigned u = hpk[0][j];           // pair h[2j], h[2j+1]
        const half2v hh = __builtin_bit_cast(half2v, u);
        const float2 wf = reinterpret_cast<const float2*>(Wfc)[j];
        float v = (float)hh[0] * wf.x + (float)hh[1] * wf.y;
        #pragma unroll
        for (int off = 32; off > 0; off >>= 1) v += __shfl_down(v, off);
        if (j == 0) out[b] = v + bfc[0];
    }
}

// ---------------------------------------------------------------------------
extern "C" void kernel_launch(void* const* d_in, const int* in_sizes, int n_in,
                              void* d_out, int out_size, void* d_ws, size_t ws_size,
                              hipStream_t stream)
{
    const float* x   = (const float*)d_in[0];
    const float* Wih = (const float*)d_in[1];
    const float* Whh = (const float*)d_in[2];
    const float* bih = (const float*)d_in[3];
    const float* bhh = (const float*)d_in[4];
    const float* Wfc = (const float*)d_in[5];
    const float* bfc = (const float*)d_in[6];
    float* out = (float*)d_out;
    float* xp  = (float*)d_ws;                       // 32 MB scratch
    short* Wb  = (short*)((char*)d_ws + (size_t)B_ * T_ * H_ * sizeof(float));  // 0.5 MB bf16 W_ih

    convW<<<dim3((H_ * I_) / (256 * 8)), dim3(256), 0, stream>>>(Wih, Wb);
    proj_mfma<<<dim3((B_ * T_) / BM), dim3(256), 0, stream>>>(x, Wb, bih, bhh, xp);
    scan_kernel<<<dim3(B_), dim3(128), 0, stream>>>(xp, Whh, Wfc, bfc, out);
}